// Round 5
// baseline (635.122 us; speedup 1.0000x reference)
//
#include <hip/hip_runtime.h>

#define N_SRC   100000
#define N_TGT   50000
#define N_EDGES 1000000
#define NEG     0.2

// ===========================================================================
// CSR/CSC build + gather. All edge-score math in f64 so summation order
// cannot move the result (denominators nearly cancel for some rows).
// ===========================================================================

// ---------------------------------------------------------------------------
// GEMM v3: msg = x @ w (K=128, N=64). Block = 64 threads = 1 wave.
// Lane = one row. x tile (64 rows) staged in LDS with stride 133 (conflict-
// free per-lane row reads); w read via wave-uniform addresses -> s_load;
// acc[64] in VGPRs -> FMA-bound (~128 cy/row).
// evec[row] = msg[row] . att[att_off:+64] accumulated in f64 (c ascending).
// ---------------------------------------------------------------------------
#define XSTRIDE 133
__global__ __launch_bounds__(64) void gemm_rowlds(
    const float* __restrict__ x, const float* __restrict__ w,
    const float* __restrict__ att, int att_off, int nrows,
    float* __restrict__ msg, double* __restrict__ evec)
{
    __shared__ float xs[64 * XSTRIDE];
    const int lane = threadIdx.x;            // 0..63
    const int row0 = blockIdx.x * 64;

    // stage 64 rows x 128 floats, coalesced float4 global reads,
    // scalar LDS writes (stride 133 keeps b32 alignment trivial)
    #pragma unroll
    for (int j = 0; j < 32; ++j) {
        const int fid = lane + 64 * j;       // float4 id within tile, 0..2047
        const int r = fid >> 5, q = fid & 31;
        if (row0 + r < nrows) {
            const float4 v = ((const float4*)(x + (size_t)row0 * 128))[fid];
            const int d = r * XSTRIDE + 4 * q;
            xs[d] = v.x; xs[d + 1] = v.y; xs[d + 2] = v.z; xs[d + 3] = v.w;
        }
    }
    __syncthreads();

    float acc[64];
    #pragma unroll
    for (int c = 0; c < 64; ++c) acc[c] = 0.f;

    const int xbase = lane * XSTRIDE;
    for (int kc = 0; kc < 128; kc += 16) {   // 8 chunks
        #pragma unroll
        for (int kk = 0; kk < 16; ++kk) {
            const float xk = xs[xbase + kc + kk];
            const float* wr = w + (size_t)(kc + kk) * 64;  // wave-uniform -> s_load
            #pragma unroll
            for (int c = 0; c < 64; ++c)
                acc[c] = fmaf(xk, wr[c], acc[c]);
        }
    }

    const int row = row0 + lane;
    if (row >= nrows) return;

    double e = 0.0;
    #pragma unroll
    for (int c = 0; c < 64; ++c) e += (double)acc[c] * (double)att[att_off + c];
    evec[row] = e;

    // per-lane row write: 16 dwordx4, lanes cover a contiguous 16 KB tile;
    // L2 merges sectors -> full-line HBM writes.
    float* mo = msg + (size_t)row * 64;
    #pragma unroll
    for (int q = 0; q < 16; ++q)
        *(float4*)(mo + 4 * q) = *(float4*)(acc + 4 * q);
}

// ---------------------------------------------------------------------------
__global__ __launch_bounds__(256) void hist_kernel(
    const int* __restrict__ rows, const int* __restrict__ cols,
    int* __restrict__ cnt_r, int* __restrict__ cnt_c)
{
    const int i = blockIdx.x * blockDim.x + threadIdx.x;
    if (i >= N_EDGES) return;
    atomicAdd(&cnt_r[rows[i]], 1);
    atomicAdd(&cnt_c[cols[i]], 1);
}

// ---------------------------------------------------------------------------
// Exclusive scan, tiled + coalesced. block 0 -> rows (N_TGT), 1 -> cols (N_SRC).
// ---------------------------------------------------------------------------
__global__ __launch_bounds__(1024) void scan_two(
    const int* __restrict__ cnt_r, const int* __restrict__ cnt_c,
    int* __restrict__ ptr_r, int* __restrict__ ofs_r,
    int* __restrict__ ptr_c, int* __restrict__ ofs_c)
{
    const int n    = blockIdx.x ? N_SRC : N_TGT;
    const int* cnt = blockIdx.x ? cnt_c : cnt_r;
    int* ptr       = blockIdx.x ? ptr_c : ptr_r;
    int* ofs       = blockIdx.x ? ofs_c : ofs_r;
    const int tid  = threadIdx.x;
    const int lane = tid & 63, wid = tid >> 6;

    __shared__ int wsum[16];
    __shared__ int s_carry;
    if (tid == 0) s_carry = 0;
    __syncthreads();

    for (int base = 0; base < n; base += 4096) {
        const int idx = base + tid * 4;
        int4 v = make_int4(0, 0, 0, 0);
        if (idx + 3 < n) {
            v = *(const int4*)(cnt + idx);
        } else if (idx < n) {
            v.x = cnt[idx];
            if (idx + 1 < n) v.y = cnt[idx + 1];
            if (idx + 2 < n) v.z = cnt[idx + 2];
        }
        const int s = v.x + v.y + v.z + v.w;

        int p = s;
        #pragma unroll
        for (int d = 1; d < 64; d <<= 1) {
            int t = __shfl_up(p, d);
            if (lane >= d) p += t;
        }
        if (lane == 63) wsum[wid] = p;
        __syncthreads();
        if (tid == 0) {
            int a = 0;
            #pragma unroll
            for (int i = 0; i < 16; ++i) { int t = wsum[i]; wsum[i] = a; a += t; }
        }
        __syncthreads();

        int run = s_carry + wsum[wid] + (p - s);
        if (idx     < n) { ptr[idx]     = run; ofs[idx]     = run; } run += v.x;
        if (idx + 1 < n) { ptr[idx + 1] = run; ofs[idx + 1] = run; } run += v.y;
        if (idx + 2 < n) { ptr[idx + 2] = run; ofs[idx + 2] = run; } run += v.z;
        if (idx + 3 < n) { ptr[idx + 3] = run; ofs[idx + 3] = run; } run += v.w;

        __syncthreads();
        if (tid == 1023) s_carry = run;
        __syncthreads();
    }
    if (tid == 0) ptr[n] = s_carry;
}

// ---------------------------------------------------------------------------
// Scatter edge IDs into both sorted lists (4 B payload; halves write traffic).
// ---------------------------------------------------------------------------
__global__ __launch_bounds__(256) void scatter_kernel(
    const int* __restrict__ rows, const int* __restrict__ cols,
    int* __restrict__ ofs_r, int* __restrict__ ofs_c,
    int* __restrict__ srtT, int* __restrict__ srtS)
{
    const int i = blockIdx.x * blockDim.x + threadIdx.x;
    if (i >= N_EDGES) return;
    const int r = rows[i], c = cols[i];
    const int p = atomicAdd(&ofs_r[r], 1);
    srtT[p] = i;
    const int q = atomicAdd(&ofs_c[c], 1);
    srtS[q] = i;
}

// ---------------------------------------------------------------------------
// Gather: one wave per output row, lane = feature. Edge data fetched via
// edge id; score v recomputed in f64; den/acc accumulated in f64.
// ---------------------------------------------------------------------------
__global__ __launch_bounds__(256) void gather_both(
    const int* __restrict__ srtT, const int* __restrict__ ptr_r,
    const float* __restrict__ s_msg, float* __restrict__ msg_tgt,
    const int* __restrict__ srtS, const int* __restrict__ ptr_c,
    const float* __restrict__ t_msg, float* __restrict__ msg_src,
    const double* __restrict__ es_d, const double* __restrict__ et_d,
    const int* __restrict__ rows, const int* __restrict__ cols,
    const float* __restrict__ nbhd)
{
    const int gw   = (blockIdx.x * blockDim.x + threadIdx.x) >> 6;
    const int lane = threadIdx.x & 63;

    const int* srt; const int* ptr; const float* min_; float* out;
    const int* oth; const double* other_d; double base; int row;
    if (gw < N_TGT) {
        srt = srtT; ptr = ptr_r; min_ = s_msg; out = msg_tgt;
        oth = cols; other_d = es_d; row = gw; base = et_d[row];
    } else {
        row = gw - N_TGT;
        if (row >= N_SRC) return;
        srt = srtS; ptr = ptr_c; min_ = t_msg; out = msg_src;
        oth = rows; other_d = et_d; base = es_d[row];
    }

    const int b = ptr[row], e = ptr[row + 1];
    double den = 0.0, acc = 0.0;

    for (int j0 = b; j0 < e; j0 += 64) {
        const int m = e - j0;
        int oidx = 0; double v = 0.0; float wf = 0.f;
        if (lane < m) {
            const int eid = srt[j0 + lane];
            oidx = oth[eid];
            const float nb = nbhd[eid];
            const double sv = base + other_d[oidx];
            v = (sv >= 0.0) ? sv : NEG * sv;
            wf = (float)(v * (double)nb);
        }
        den += v;

        const int cnt = m < 64 ? m : 64;
        for (int j = 0; j < cnt; ++j) {
            const int   c = __shfl(oidx, j);
            const float w = __shfl(wf, j);
            acc += (double)w * (double)min_[(size_t)c * 64 + lane];
        }
    }
    #pragma unroll
    for (int s = 32; s; s >>= 1) den += __shfl_xor(den, s);
    const double inv = (den != 0.0) ? 1.0 / den : 0.0;
    out[(size_t)row * 64 + lane] = (float)(acc * inv);
}

// ===========================================================================
extern "C" void kernel_launch(void* const* d_in, const int* in_sizes, int n_in,
                              void* d_out, int out_size, void* d_ws, size_t ws_size,
                              hipStream_t stream)
{
    const float* x_source = (const float*)d_in[0];
    const float* x_target = (const float*)d_in[1];
    const float* w_s      = (const float*)d_in[2];
    const float* w_t      = (const float*)d_in[3];
    const float* att      = (const float*)d_in[4];
    const float* nbhd     = (const float*)d_in[5];
    const int*   rows     = (const int*)d_in[6];
    const int*   cols     = (const int*)d_in[7];

    float* out     = (float*)d_out;
    float* msg_src = out;                       // (N_SRC, 64)
    float* msg_tgt = out + (size_t)N_SRC * 64;  // (N_TGT, 64)

    char* ws = (char*)d_ws;
    // byte layout: total 49,400,008 B
    float*  s_msg = (float*) (ws + 0);           // 25,600,000
    float*  t_msg = (float*) (ws + 25600000);    // 12,800,000
    double* es_d  = (double*)(ws + 38400000);    //    800,000
    double* et_d  = (double*)(ws + 39200000);    //    400,000
    int*    cnt_r = (int*)   (ws + 39600000);    //    200,000
    int*    cnt_c = (int*)   (ws + 39800000);    //    400,000
    int*    ptr_r = (int*)   (ws + 40200000);    //    200,004
    int*    ptr_c = (int*)   (ws + 40400004);    //    400,004
    int*    ofs_r = (int*)   (ws + 40800008);    //    200,000
    int*    ofs_c = (int*)   (ws + 41000008);    //    400,000
    int*    srtT  = (int*)   (ws + 41400008);    //  4,000,000
    int*    srtS  = (int*)   (ws + 45400008);    //  4,000,000

    hipMemsetAsync(ws + 39600000, 0, 600000, stream);  // cnt_r + cnt_c

    gemm_rowlds<<<(N_SRC + 63) / 64, 64, 0, stream>>>(
        x_source, w_s, att, 0, N_SRC, s_msg, es_d);
    gemm_rowlds<<<(N_TGT + 63) / 64, 64, 0, stream>>>(
        x_target, w_t, att, 64, N_TGT, t_msg, et_d);

    hist_kernel<<<(N_EDGES + 255) / 256, 256, 0, stream>>>(rows, cols, cnt_r, cnt_c);
    scan_two<<<2, 1024, 0, stream>>>(cnt_r, cnt_c, ptr_r, ofs_r, ptr_c, ofs_c);
    scatter_kernel<<<(N_EDGES + 255) / 256, 256, 0, stream>>>(
        rows, cols, ofs_r, ofs_c, srtT, srtS);

    gather_both<<<(N_TGT + N_SRC + 3) / 4, 256, 0, stream>>>(
        srtT, ptr_r, s_msg, msg_tgt, srtS, ptr_c, t_msg, msg_src,
        es_d, et_d, rows, cols, nbhd);
}

// Round 7
// 615.178 us; speedup vs baseline: 1.0324x; 1.0324x over previous
//
#include <hip/hip_runtime.h>

#define N_SRC   100000
#define N_TGT   50000
#define N_EDGES 1000000
#define NEG     0.2

// ===========================================================================
// CSR/CSC build + gather. Edge-score math in f64 (ill-conditioned row sums);
// msg matrices f32 (bf16 proved numerically fatal in R6).
// ===========================================================================

// ---------------------------------------------------------------------------
// GEMM: msg = x @ w (K=128, N=64). 256 threads = 256 rows per block.
// x staged through LDS in 16-k chunks with fully coalesced global reads
// (64 B per 4 lanes); pad 17 makes per-lane row reads bank-conflict-free.
// w rows are wave-uniform -> scalar loads. acc[64] in VGPRs (FMA-bound).
// evec[row] = msg[row] . att[att_off:+64] accumulated in f64 (c ascending,
// identical order to R3/R4/R5 -> bit-identical results).
// ---------------------------------------------------------------------------
#define XPAD 17
__global__ __launch_bounds__(256) void gemm_tile(
    const float* __restrict__ x, const float* __restrict__ w,
    const float* __restrict__ att, int att_off, int nrows,
    float* __restrict__ msg, double* __restrict__ evec)
{
    __shared__ float xs[256 * XPAD];           // 17.4 KB
    const int tid  = threadIdx.x;
    const int row0 = blockIdx.x * 256;
    const int row  = row0 + tid;

    float acc[64];
    #pragma unroll
    for (int c = 0; c < 64; ++c) acc[c] = 0.f;

    for (int kc = 0; kc < 128; kc += 16) {     // 8 chunks
        __syncthreads();                       // xs reuse guard
        #pragma unroll
        for (int j = 0; j < 4; ++j) {          // stage 256x16 tile, 4 float4/thread
            const int fid = tid + 256 * j;     // 0..1023
            const int r = fid >> 2, q = fid & 3;
            if (row0 + r < nrows) {
                const float4 v = *(const float4*)(x + (size_t)(row0 + r) * 128 + kc + 4 * q);
                const int d = r * XPAD + 4 * q;
                xs[d] = v.x; xs[d + 1] = v.y; xs[d + 2] = v.z; xs[d + 3] = v.w;
            }
        }
        __syncthreads();

        #pragma unroll
        for (int kk = 0; kk < 16; ++kk) {
            const float xk = xs[tid * XPAD + kk];
            const float* wr = w + (size_t)(kc + kk) * 64;   // wave-uniform -> s_load
            #pragma unroll
            for (int c = 0; c < 64; ++c)
                acc[c] = fmaf(xk, wr[c], acc[c]);
        }
    }
    if (row >= nrows) return;

    double e = 0.0;
    #pragma unroll
    for (int c = 0; c < 64; ++c) e += (double)acc[c] * (double)att[att_off + c];
    evec[row] = e;

    float* mo = msg + (size_t)row * 64;
    #pragma unroll
    for (int q = 0; q < 16; ++q)
        *(float4*)(mo + 4 * q) = *(float4*)(acc + 4 * q);
}

// ---------------------------------------------------------------------------
__global__ __launch_bounds__(256) void hist_kernel(
    const int* __restrict__ rows, const int* __restrict__ cols,
    int* __restrict__ cnt_r, int* __restrict__ cnt_c)
{
    const int i = blockIdx.x * blockDim.x + threadIdx.x;
    if (i >= N_EDGES) return;
    atomicAdd(&cnt_r[rows[i]], 1);
    atomicAdd(&cnt_c[cols[i]], 1);
}

// ---------------------------------------------------------------------------
// Exclusive scan, tiled + coalesced. block 0 -> rows (N_TGT), 1 -> cols (N_SRC).
// ---------------------------------------------------------------------------
__global__ __launch_bounds__(1024) void scan_two(
    const int* __restrict__ cnt_r, const int* __restrict__ cnt_c,
    int* __restrict__ ptr_r, int* __restrict__ ofs_r,
    int* __restrict__ ptr_c, int* __restrict__ ofs_c)
{
    const int n    = blockIdx.x ? N_SRC : N_TGT;
    const int* cnt = blockIdx.x ? cnt_c : cnt_r;
    int* ptr       = blockIdx.x ? ptr_c : ptr_r;
    int* ofs       = blockIdx.x ? ofs_c : ofs_r;
    const int tid  = threadIdx.x;
    const int lane = tid & 63, wid = tid >> 6;

    __shared__ int wsum[16];
    __shared__ int s_carry;
    if (tid == 0) s_carry = 0;
    __syncthreads();

    for (int base = 0; base < n; base += 4096) {
        const int idx = base + tid * 4;
        int4 v = make_int4(0, 0, 0, 0);
        if (idx + 3 < n) {
            v = *(const int4*)(cnt + idx);
        } else if (idx < n) {
            v.x = cnt[idx];
            if (idx + 1 < n) v.y = cnt[idx + 1];
            if (idx + 2 < n) v.z = cnt[idx + 2];
        }
        const int s = v.x + v.y + v.z + v.w;

        int p = s;
        #pragma unroll
        for (int d = 1; d < 64; d <<= 1) {
            int t = __shfl_up(p, d);
            if (lane >= d) p += t;
        }
        if (lane == 63) wsum[wid] = p;
        __syncthreads();
        if (tid == 0) {
            int a = 0;
            #pragma unroll
            for (int i = 0; i < 16; ++i) { int t = wsum[i]; wsum[i] = a; a += t; }
        }
        __syncthreads();

        int run = s_carry + wsum[wid] + (p - s);
        if (idx     < n) { ptr[idx]     = run; ofs[idx]     = run; } run += v.x;
        if (idx + 1 < n) { ptr[idx + 1] = run; ofs[idx + 1] = run; } run += v.y;
        if (idx + 2 < n) { ptr[idx + 2] = run; ofs[idx + 2] = run; } run += v.z;
        if (idx + 3 < n) { ptr[idx + 3] = run; ofs[idx + 3] = run; } run += v.w;

        __syncthreads();
        if (tid == 1023) s_carry = run;
        __syncthreads();
    }
    if (tid == 0) ptr[n] = s_carry;
}

// ---------------------------------------------------------------------------
// Scatter: payload (other_idx, nbhd) packed in one 8 B NONTEMPORAL store
// (no L2 allocate -> test whether the 64B dirty-line write amplification
// seen in R4/R5 disappears).
// ---------------------------------------------------------------------------
__global__ __launch_bounds__(256) void scatter_kernel(
    const int* __restrict__ rows, const int* __restrict__ cols,
    const float* __restrict__ nbhd,
    int* __restrict__ ofs_r, int* __restrict__ ofs_c,
    unsigned long long* __restrict__ srtT, unsigned long long* __restrict__ srtS)
{
    const int i = blockIdx.x * blockDim.x + threadIdx.x;
    if (i >= N_EDGES) return;
    const int r = rows[i], c = cols[i];
    const unsigned nb = (unsigned)__float_as_int(nbhd[i]);
    const int p = atomicAdd(&ofs_r[r], 1);
    __builtin_nontemporal_store(((unsigned long long)nb << 32) | (unsigned)c, &srtT[p]);
    const int q = atomicAdd(&ofs_c[c], 1);
    __builtin_nontemporal_store(((unsigned long long)nb << 32) | (unsigned)r, &srtS[q]);
}

// ---------------------------------------------------------------------------
// Gather: one wave per output row, lane = feature. Scores recomputed in f64
// from es_d/et_d (1.2 MB total -> L2-resident); den/acc in f64; msg f32.
// ---------------------------------------------------------------------------
__global__ __launch_bounds__(256) void gather_both(
    const int2* __restrict__ srtT, const int* __restrict__ ptr_r,
    const float* __restrict__ s_msg, float* __restrict__ msg_tgt,
    const int2* __restrict__ srtS, const int* __restrict__ ptr_c,
    const float* __restrict__ t_msg, float* __restrict__ msg_src,
    const double* __restrict__ es_d, const double* __restrict__ et_d)
{
    const int gw   = (blockIdx.x * blockDim.x + threadIdx.x) >> 6;
    const int lane = threadIdx.x & 63;

    const int2* srt; const int* ptr; const float* min_; float* out;
    const double* other_d; double base; int row;
    if (gw < N_TGT) {
        srt = srtT; ptr = ptr_r; min_ = s_msg; out = msg_tgt;
        other_d = es_d; row = gw; base = et_d[row];
    } else {
        row = gw - N_TGT;
        if (row >= N_SRC) return;
        srt = srtS; ptr = ptr_c; min_ = t_msg; out = msg_src;
        other_d = et_d; base = es_d[row];
    }

    const int b = ptr[row], e = ptr[row + 1];
    double den = 0.0, acc = 0.0;

    for (int j0 = b; j0 < e; j0 += 64) {
        const int m = e - j0;
        int oidx = 0; double v = 0.0; float wf = 0.f;
        if (lane < m) {
            const int2 pay = srt[j0 + lane];
            oidx = pay.x;
            const float nb = __int_as_float(pay.y);
            const double sv = base + other_d[oidx];
            v = (sv >= 0.0) ? sv : NEG * sv;
            wf = (float)(v * (double)nb);
        }
        den += v;

        const int cnt = m < 64 ? m : 64;
        for (int j = 0; j < cnt; ++j) {
            const int   c = __shfl(oidx, j);
            const float w = __shfl(wf, j);
            acc += (double)w * (double)min_[(size_t)c * 64 + lane];
        }
    }
    #pragma unroll
    for (int s = 32; s; s >>= 1) den += __shfl_xor(den, s);
    const double inv = (den != 0.0) ? 1.0 / den : 0.0;
    __builtin_nontemporal_store((float)(acc * inv), &out[(size_t)row * 64 + lane]);
}

// ===========================================================================
extern "C" void kernel_launch(void* const* d_in, const int* in_sizes, int n_in,
                              void* d_out, int out_size, void* d_ws, size_t ws_size,
                              hipStream_t stream)
{
    const float* x_source = (const float*)d_in[0];
    const float* x_target = (const float*)d_in[1];
    const float* w_s      = (const float*)d_in[2];
    const float* w_t      = (const float*)d_in[3];
    const float* att      = (const float*)d_in[4];
    const float* nbhd     = (const float*)d_in[5];
    const int*   rows     = (const int*)d_in[6];
    const int*   cols     = (const int*)d_in[7];

    float* out     = (float*)d_out;
    float* msg_src = out;                       // (N_SRC, 64)
    float* msg_tgt = out + (size_t)N_SRC * 64;  // (N_TGT, 64)

    char* ws = (char*)d_ws;
    // byte layout: total 57,400,016 B
    float*  s_msg = (float*) (ws + 0);           // 25,600,000
    float*  t_msg = (float*) (ws + 25600000);    // 12,800,000
    double* es_d  = (double*)(ws + 38400000);    //    800,000
    double* et_d  = (double*)(ws + 39200000);    //    400,000
    int*    cnt_r = (int*)   (ws + 39600000);    //    200,000
    int*    cnt_c = (int*)   (ws + 39800000);    //    400,000
    int*    ptr_r = (int*)   (ws + 40200000);    //    200,004
    int*    ptr_c = (int*)   (ws + 40400004);    //    400,004
    int*    ofs_r = (int*)   (ws + 40800008);    //    200,000
    int*    ofs_c = (int*)   (ws + 41000008);    //    400,000 (+8 pad)
    unsigned long long* srtT = (unsigned long long*)(ws + 41400016); // 8,000,000
    unsigned long long* srtS = (unsigned long long*)(ws + 49400016); // 8,000,000

    hipMemsetAsync(ws + 39600000, 0, 600000, stream);  // cnt_r + cnt_c

    gemm_tile<<<(N_SRC + 255) / 256, 256, 0, stream>>>(
        x_source, w_s, att, 0, N_SRC, s_msg, es_d);
    gemm_tile<<<(N_TGT + 255) / 256, 256, 0, stream>>>(
        x_target, w_t, att, 64, N_TGT, t_msg, et_d);

    hist_kernel<<<(N_EDGES + 255) / 256, 256, 0, stream>>>(rows, cols, cnt_r, cnt_c);
    scan_two<<<2, 1024, 0, stream>>>(cnt_r, cnt_c, ptr_r, ofs_r, ptr_c, ofs_c);
    scatter_kernel<<<(N_EDGES + 255) / 256, 256, 0, stream>>>(
        rows, cols, nbhd, ofs_r, ofs_c, srtT, srtS);

    gather_both<<<(N_TGT + N_SRC + 3) / 4, 256, 0, stream>>>(
        (const int2*)srtT, ptr_r, s_msg, msg_tgt,
        (const int2*)srtS, ptr_c, t_msg, msg_src, es_d, et_d);
}

// Round 8
// 494.796 us; speedup vs baseline: 1.2836x; 1.2433x over previous
//
#include <hip/hip_runtime.h>

#define N_SRC   100000
#define N_TGT   50000
#define N_EDGES 1000000
#define NEG     0.2
#define NXCD    8
#define TPART   (N_TGT / NXCD)   // 6250
#define SPART   (N_SRC / NXCD)   // 12500

// ===========================================================================
// CSR/CSC build + gather. Edge-score math in f64 (ill-conditioned row sums);
// msg matrices f32 (bf16 fatal, R6). Scatter/hist are XCD-partitioned so each
// XCD's random writes stay inside its own L2 (R7: write-amp = 126 MB).
// ===========================================================================

// ---------------------------------------------------------------------------
// GEMM (R3 rowlane, measured-best ~130 us/pair): one lane per row, acc[64]
// in VGPRs, w rows wave-uniform -> s_load. msg f32; evec f64.
// ---------------------------------------------------------------------------
__global__ __launch_bounds__(256) void gemm_rowlane(
    const float* __restrict__ x, const float* __restrict__ w,
    const float* __restrict__ att, int att_off, int nrows,
    float* __restrict__ msg, double* __restrict__ evec)
{
    const int row = blockIdx.x * blockDim.x + threadIdx.x;
    if (row >= nrows) return;
    const float* xr = x + (size_t)row * 128;

    float acc[64];
    #pragma unroll
    for (int c = 0; c < 64; ++c) acc[c] = 0.f;

    for (int kc = 0; kc < 128; kc += 16) {
        float4 xv[4];
        #pragma unroll
        for (int q = 0; q < 4; ++q)
            xv[q] = *(const float4*)(xr + kc + 4 * q);
        #pragma unroll
        for (int kk = 0; kk < 16; ++kk) {
            const float xk = ((const float*)xv)[kk];
            const float* wr = w + (size_t)(kc + kk) * 64;   // wave-uniform
            #pragma unroll
            for (int c = 0; c < 64; ++c)
                acc[c] = fmaf(xk, wr[c], acc[c]);
        }
    }

    double e = 0.0;
    #pragma unroll
    for (int c = 0; c < 64; ++c) e += (double)acc[c] * (double)att[att_off + c];
    evec[row] = e;

    float* mo = msg + (size_t)row * 64;
    #pragma unroll
    for (int q = 0; q < 16; ++q)
        *(float4*)(mo + 4 * q) = *(float4*)(acc + 4 * q);
}

// ---------------------------------------------------------------------------
// Histogram, XCD-partitioned: XCD k only counts nodes in its partition, so
// each counter line lives in exactly one L2 (no cross-XCD atomic bouncing).
// Edges are re-read 8x (L3-absorbed).
// ---------------------------------------------------------------------------
__global__ __launch_bounds__(256) void hist_part(
    const int* __restrict__ rows, const int* __restrict__ cols,
    int* __restrict__ cnt_r, int* __restrict__ cnt_c)
{
    const int xcd  = blockIdx.x & (NXCD - 1);
    const int ibx  = blockIdx.x >> 3;
    const int step = (gridDim.x >> 3) * blockDim.x;
    const int lo_r = xcd * TPART, lo_c = xcd * SPART;

    for (int i = ibx * blockDim.x + threadIdx.x; i < N_EDGES; i += step) {
        const int r = rows[i], c = cols[i];
        if ((unsigned)(r - lo_r) < TPART) atomicAdd(&cnt_r[r], 1);
        if ((unsigned)(c - lo_c) < SPART) atomicAdd(&cnt_c[c], 1);
    }
}

// ---------------------------------------------------------------------------
// Exclusive scan, tiled + coalesced. block 0 -> rows (N_TGT), 1 -> cols (N_SRC).
// ---------------------------------------------------------------------------
__global__ __launch_bounds__(1024) void scan_two(
    const int* __restrict__ cnt_r, const int* __restrict__ cnt_c,
    int* __restrict__ ptr_r, int* __restrict__ ofs_r,
    int* __restrict__ ptr_c, int* __restrict__ ofs_c)
{
    const int n    = blockIdx.x ? N_SRC : N_TGT;
    const int* cnt = blockIdx.x ? cnt_c : cnt_r;
    int* ptr       = blockIdx.x ? ptr_c : ptr_r;
    int* ofs       = blockIdx.x ? ofs_c : ofs_r;
    const int tid  = threadIdx.x;
    const int lane = tid & 63, wid = tid >> 6;

    __shared__ int wsum[16];
    __shared__ int s_carry;
    if (tid == 0) s_carry = 0;
    __syncthreads();

    for (int base = 0; base < n; base += 4096) {
        const int idx = base + tid * 4;
        int4 v = make_int4(0, 0, 0, 0);
        if (idx + 3 < n) {
            v = *(const int4*)(cnt + idx);
        } else if (idx < n) {
            v.x = cnt[idx];
            if (idx + 1 < n) v.y = cnt[idx + 1];
            if (idx + 2 < n) v.z = cnt[idx + 2];
        }
        const int s = v.x + v.y + v.z + v.w;

        int p = s;
        #pragma unroll
        for (int d = 1; d < 64; d <<= 1) {
            int t = __shfl_up(p, d);
            if (lane >= d) p += t;
        }
        if (lane == 63) wsum[wid] = p;
        __syncthreads();
        if (tid == 0) {
            int a = 0;
            #pragma unroll
            for (int i = 0; i < 16; ++i) { int t = wsum[i]; wsum[i] = a; a += t; }
        }
        __syncthreads();

        int run = s_carry + wsum[wid] + (p - s);
        if (idx     < n) { ptr[idx]     = run; ofs[idx]     = run; } run += v.x;
        if (idx + 1 < n) { ptr[idx + 1] = run; ofs[idx + 1] = run; } run += v.y;
        if (idx + 2 < n) { ptr[idx + 2] = run; ofs[idx + 2] = run; } run += v.z;
        if (idx + 3 < n) { ptr[idx + 3] = run; ofs[idx + 3] = run; } run += v.w;

        __syncthreads();
        if (tid == 1023) s_carry = run;
        __syncthreads();
    }
    if (tid == 0) ptr[n] = s_carry;
}

// ---------------------------------------------------------------------------
// Scatter, XCD-partitioned: XCD k claims edges with r (resp. c) in its
// partition. Its payload writes span a private ~1-2 MB contiguous region ->
// lines fill up inside ONE L2 and write back whole (no partial-line amp).
// ---------------------------------------------------------------------------
__global__ __launch_bounds__(256) void scatter_part(
    const int* __restrict__ rows, const int* __restrict__ cols,
    const float* __restrict__ nbhd,
    int* __restrict__ ofs_r, int* __restrict__ ofs_c,
    unsigned long long* __restrict__ srtT, unsigned long long* __restrict__ srtS)
{
    const int xcd  = blockIdx.x & (NXCD - 1);
    const int ibx  = blockIdx.x >> 3;
    const int step = (gridDim.x >> 3) * blockDim.x;
    const int lo_r = xcd * TPART, lo_c = xcd * SPART;

    for (int i = ibx * blockDim.x + threadIdx.x; i < N_EDGES; i += step) {
        const int r = rows[i], c = cols[i];
        const bool mr = (unsigned)(r - lo_r) < TPART;
        const bool mc = (unsigned)(c - lo_c) < SPART;
        if (!(mr | mc)) continue;
        const unsigned long long nb =
            (unsigned long long)(unsigned)__float_as_int(nbhd[i]) << 32;
        if (mr) { const int p = atomicAdd(&ofs_r[r], 1); srtT[p] = nb | (unsigned)c; }
        if (mc) { const int q = atomicAdd(&ofs_c[c], 1); srtS[q] = nb | (unsigned)r; }
    }
}

// ---------------------------------------------------------------------------
// Gather: one wave per output row, lane = feature. Scores recomputed in f64
// from es_d/et_d (1.2 MB, L2-resident); den/acc in f64; msg f32.
// ---------------------------------------------------------------------------
__global__ __launch_bounds__(256) void gather_both(
    const int2* __restrict__ srtT, const int* __restrict__ ptr_r,
    const float* __restrict__ s_msg, float* __restrict__ msg_tgt,
    const int2* __restrict__ srtS, const int* __restrict__ ptr_c,
    const float* __restrict__ t_msg, float* __restrict__ msg_src,
    const double* __restrict__ es_d, const double* __restrict__ et_d)
{
    const int gw   = (blockIdx.x * blockDim.x + threadIdx.x) >> 6;
    const int lane = threadIdx.x & 63;

    const int2* srt; const int* ptr; const float* min_; float* out;
    const double* other_d; double base; int row;
    if (gw < N_TGT) {
        srt = srtT; ptr = ptr_r; min_ = s_msg; out = msg_tgt;
        other_d = es_d; row = gw; base = et_d[row];
    } else {
        row = gw - N_TGT;
        if (row >= N_SRC) return;
        srt = srtS; ptr = ptr_c; min_ = t_msg; out = msg_src;
        other_d = et_d; base = es_d[row];
    }

    const int b = ptr[row], e = ptr[row + 1];
    double den = 0.0, acc = 0.0;

    for (int j0 = b; j0 < e; j0 += 64) {
        const int m = e - j0;
        int oidx = 0; double v = 0.0; float wf = 0.f;
        if (lane < m) {
            const int2 pay = srt[j0 + lane];
            oidx = pay.x;
            const float nb = __int_as_float(pay.y);
            const double sv = base + other_d[oidx];
            v = (sv >= 0.0) ? sv : NEG * sv;
            wf = (float)(v * (double)nb);
        }
        den += v;

        const int cnt = m < 64 ? m : 64;
        for (int j = 0; j < cnt; ++j) {
            const int   c = __shfl(oidx, j);
            const float w = __shfl(wf, j);
            acc += (double)w * (double)min_[(size_t)c * 64 + lane];
        }
    }
    #pragma unroll
    for (int s = 32; s; s >>= 1) den += __shfl_xor(den, s);
    const double inv = (den != 0.0) ? 1.0 / den : 0.0;
    out[(size_t)row * 64 + lane] = (float)(acc * inv);
}

// ===========================================================================
extern "C" void kernel_launch(void* const* d_in, const int* in_sizes, int n_in,
                              void* d_out, int out_size, void* d_ws, size_t ws_size,
                              hipStream_t stream)
{
    const float* x_source = (const float*)d_in[0];
    const float* x_target = (const float*)d_in[1];
    const float* w_s      = (const float*)d_in[2];
    const float* w_t      = (const float*)d_in[3];
    const float* att      = (const float*)d_in[4];
    const float* nbhd     = (const float*)d_in[5];
    const int*   rows     = (const int*)d_in[6];
    const int*   cols     = (const int*)d_in[7];

    float* out     = (float*)d_out;
    float* msg_src = out;                       // (N_SRC, 64)
    float* msg_tgt = out + (size_t)N_SRC * 64;  // (N_TGT, 64)

    char* ws = (char*)d_ws;
    // byte layout: total 57,400,016 B
    float*  s_msg = (float*) (ws + 0);           // 25,600,000
    float*  t_msg = (float*) (ws + 25600000);    // 12,800,000
    double* es_d  = (double*)(ws + 38400000);    //    800,000
    double* et_d  = (double*)(ws + 39200000);    //    400,000
    int*    cnt_r = (int*)   (ws + 39600000);    //    200,000
    int*    cnt_c = (int*)   (ws + 39800000);    //    400,000
    int*    ptr_r = (int*)   (ws + 40200000);    //    200,004
    int*    ptr_c = (int*)   (ws + 40400004);    //    400,004
    int*    ofs_r = (int*)   (ws + 40800008);    //    200,000
    int*    ofs_c = (int*)   (ws + 41000008);    //    400,000 (+8 pad)
    unsigned long long* srtT = (unsigned long long*)(ws + 41400016); // 8,000,000
    unsigned long long* srtS = (unsigned long long*)(ws + 49400016); // 8,000,000

    hipMemsetAsync(ws + 39600000, 0, 600000, stream);  // cnt_r + cnt_c

    gemm_rowlane<<<(N_SRC + 255) / 256, 256, 0, stream>>>(
        x_source, w_s, att, 0, N_SRC, s_msg, es_d);
    gemm_rowlane<<<(N_TGT + 255) / 256, 256, 0, stream>>>(
        x_target, w_t, att, 64, N_TGT, t_msg, et_d);

    hist_part<<<2048, 256, 0, stream>>>(rows, cols, cnt_r, cnt_c);
    scan_two<<<2, 1024, 0, stream>>>(cnt_r, cnt_c, ptr_r, ofs_r, ptr_c, ofs_c);
    scatter_part<<<2048, 256, 0, stream>>>(
        rows, cols, nbhd, ofs_r, ofs_c, srtT, srtS);

    gather_both<<<(N_TGT + N_SRC + 3) / 4, 256, 0, stream>>>(
        (const int2*)srtT, ptr_r, s_msg, msg_tgt,
        (const int2*)srtS, ptr_c, t_msg, msg_src, es_d, et_d);
}